// Round 7
// baseline (651.181 us; speedup 1.0000x reference)
//
#include <hip/hip_runtime.h>
#include <cstdint>

#define DIN 16
#define HD  128
#define NB  256     // grid = #CUs: all blocks co-resident (1024 thr = 16 waves <= 32/CU)
#define NT  1024
#define RNG 512     // nodes per bin
#define LB  9       // log2(RNG)
#define MAXB 256    // padded bin array
#define CAP 6144    // per-bin edge capacity (mean 4082, sigma ~64)

static __device__ __forceinline__ void fma4(float4& a, float s, const float4 v) {
    a.x = fmaf(s, v.x, a.x);
    a.y = fmaf(s, v.y, a.y);
    a.z = fmaf(s, v.z, a.z);
    a.w = fmaf(s, v.w, a.w);
}
static __device__ __forceinline__ void add4(float4& a, const float4 v) {
    a.x += v.x; a.y += v.y; a.z += v.z; a.w += v.w;
}
static __device__ __forceinline__ void lrelu4(float4& h) {
    h.x = h.x > 0.f ? h.x : 0.01f * h.x;
    h.y = h.y > 0.f ? h.y : 0.01f * h.y;
    h.z = h.z > 0.f ? h.z : 0.01f * h.z;
    h.w = h.w > 0.f ? h.w : 0.01f * h.w;
}

// Software grid barrier, ockl-style (mirrors ROCm's __ockl_grid_sync, which R4
// proved fast+correct on this chip):
//   arrive: RELEASE fetch_add (device scope)
//   spin:   RELAXED agent atomic load (compiles to sc1 L2-bypassing plain load:
//           no buffer_inv per probe [R5's bug], no RMW serialization [R6's bug])
//   leave:  one acquire fence per thread (__threadfence) after __syncthreads.
// Bounded spin: if co-residency ever breaks we fail loudly (wrong output), not hang.
static __device__ __forceinline__ void swbar(int* bar, int target) {
    __threadfence();                 // release: this block's writes visible device-wide
    __syncthreads();
    if (threadIdx.x == 0) {
        __hip_atomic_fetch_add(bar, 1, __ATOMIC_RELEASE, __HIP_MEMORY_SCOPE_AGENT);
        int it = 0;
        while (__hip_atomic_load(bar, __ATOMIC_RELAXED,
                                 __HIP_MEMORY_SCOPE_AGENT) < target) {
            __builtin_amdgcn_s_sleep(32);        // ~0.85 us backoff
            if (++it > (1 << 18)) break;         // bounded: fail loudly, never hang
        }
    }
    __syncthreads();
    __threadfence();                 // acquire: invalidate stale cached lines once
}

__global__ __launch_bounds__(NT) void k_all(
    const float* __restrict__ F,
    const int* __restrict__ src, const int* __restrict__ dst,
    const float* __restrict__ Win, const float* __restrict__ binp,
    const float* __restrict__ W1, const float* __restrict__ b1,
    const float* __restrict__ W2, const float* __restrict__ b2,
    const float* __restrict__ Wout, const float* __restrict__ bout,
    int* __restrict__ binCnt, int* __restrict__ bar,
    int* __restrict__ ebin, int* __restrict__ ecsr, int* __restrict__ rowptr,
    float4* __restrict__ Y, float4* __restrict__ Ys, float4* __restrict__ Z1s,
    float* __restrict__ out, int N, int E, int R, int CHK)
{
    const int tid = threadIdx.x;
    const int bid = blockIdx.x;
    const int lane = tid & 63, wid = tid >> 6;

    __shared__ float  sT[HD * 3];           // W2@Wout (temp)
    __shared__ float4 sWinT[DIN * HD / 4];  // [k][c][l] : idx = k*32 + c*16 + l
    __shared__ float4 sWcT[HD];             // folded W1@W2@Wout, [jj][l]
    __shared__ float4 sBin[HD / 4];
    __shared__ float  sF[128 * DIN];
    __shared__ float  scb[8];               // c1[3], c2[3]
    __shared__ int    cnt[MAXB];
    __shared__ int    rsv[MAXB];
    __shared__ int    c[RNG];
    __shared__ int    sb[MAXB];
    __shared__ int    swv[16];
    __shared__ int    se0;

    // ============ P1a: partition — ALL blocks, CHK=E/256 edges each ============
    for (int i = tid; i < MAXB; i += NT) cnt[i] = 0;
    __syncthreads();
    int e0 = bid * CHK;
    int e1 = e0 + CHK; if (e1 > E) e1 = E;
    for (int e = e0 + tid; e < e1; e += NT) atomicAdd(&cnt[dst[e] >> LB], 1);
    __syncthreads();
    if (tid < MAXB) {
        int cc = cnt[tid];
        rsv[tid] = (tid < R && cc) ? atomicAdd(&binCnt[tid], cc) : 0;  // ~50k dev atomics
    }
    __syncthreads();
    for (int i = tid; i < MAXB; i += NT) cnt[i] = 0;   // reuse as local cursor
    __syncthreads();
    for (int e = e0 + tid; e < e1; e += NT) {
        int s = src[e], d = dst[e];
        int bb = d >> LB;
        int lp = atomicAdd(&cnt[bb], 1);               // LDS atomic
        ebin[(size_t)bb * CAP + rsv[bb] + lp] = (s << LB) | (d & (RNG - 1));
    }

    // ============ P1b: weight fold (redundant per block, all in LDS) ============
    if (tid < DIN * HD / 4) {               // stage Win (512 float4)
        int k = tid >> 5, rem = tid & 31, l = rem >> 1, cc = rem & 1;
        sWinT[k * 32 + cc * 16 + l] = ((const float4*)Win)[tid];
    } else if (tid < DIN * HD / 4 + HD / 4) {
        int i = tid - DIN * HD / 4;
        sBin[i] = ((const float4*)binp)[i];
    }
    for (int idx = tid; idx < HD * 3; idx += NT) {     // sT = W2 @ Wout
        int k = idx / 3, o = idx - 3 * k;
        float s = 0.f;
        for (int j = 0; j < HD; j++) s = fmaf(W2[k * HD + j], Wout[j * 3 + o], s);
        sT[idx] = s;
    }
    __syncthreads();
    for (int idx = tid; idx < HD * 3; idx += NT) {     // Wc = W1 @ sT
        int k = idx / 3, o = idx - 3 * k;
        float s = 0.f;
        for (int j = 0; j < HD; j++) s = fmaf(W1[k * HD + j], sT[j * 3 + o], s);
        ((float*)&sWcT[(k & 7) * 16 + (k >> 3)])[o] = s;
    }
    if (tid < HD) ((float*)&sWcT[(tid & 7) * 16 + (tid >> 3)])[3] = 0.f;
    if (tid < 3) {                          // c2 = Wout^T b2 + bout ; c1 = sT^T b1
        float s2v = bout[tid];
        for (int j = 0; j < HD; j++) s2v = fmaf(b2[j], Wout[j * 3 + tid], s2v);
        scb[3 + tid] = s2v;
        float s1 = 0.f;
        for (int j = 0; j < HD; j++) s1 = fmaf(b1[j], sT[j * 3 + tid], s1);
        scb[tid] = s1;
    }
    __syncthreads();

    // ============ P1c: input MLP — ALL blocks, 391 nodes each ============
    {
        int nper = (N + NB - 1) / NB;
        int nb0 = bid * nper;
        int nb1 = nb0 + nper; if (nb1 > N) nb1 = N;
        for (int cb = nb0; cb < nb1; cb += 128) {
            {
                int n0 = cb + (tid >> 4);
                sF[tid] = (n0 < N) ? F[(size_t)cb * DIN + tid] : 0.f;
                int n1 = cb + ((tid + 1024) >> 4);
                sF[tid + 1024] = (n1 < N) ? F[(size_t)cb * DIN + tid + 1024] : 0.f;
            }
            __syncthreads();
            int l = tid & 15;
            int g = tid >> 4;
            int nodeA = cb + 2 * g;
            int nodeB = nodeA + 1;
            if (nodeA < nb1) {
                float4 a0 = sBin[l * 2 + 0], a1 = sBin[l * 2 + 1];
                float4 b0 = a0, b1v = a1;
                #pragma unroll
                for (int k = 0; k < DIN; k++) {
                    float4 w0 = sWinT[k * 32 + l];
                    float4 w1 = sWinT[k * 32 + 16 + l];
                    float fA = sF[(2 * g) * DIN + k];
                    float fB = sF[(2 * g + 1) * DIN + k];
                    fma4(a0, fA, w0); fma4(a1, fA, w1);
                    fma4(b0, fB, w0); fma4(b1v, fB, w1);
                }
                lrelu4(a0); lrelu4(a1); lrelu4(b0); lrelu4(b1v);
                float hA[8] = {a0.x, a0.y, a0.z, a0.w, a1.x, a1.y, a1.z, a1.w};
                float hB[8] = {b0.x, b0.y, b0.z, b0.w, b1v.x, b1v.y, b1v.z, b1v.w};
                float pA0 = 0.f, pA1 = 0.f, pA2 = 0.f, pB0 = 0.f, pB1 = 0.f, pB2 = 0.f;
                #pragma unroll
                for (int jj = 0; jj < 8; jj++) {
                    float4 wc = sWcT[jj * 16 + l];
                    pA0 = fmaf(hA[jj], wc.x, pA0);
                    pA1 = fmaf(hA[jj], wc.y, pA1);
                    pA2 = fmaf(hA[jj], wc.z, pA2);
                    pB0 = fmaf(hB[jj], wc.x, pB0);
                    pB1 = fmaf(hB[jj], wc.y, pB1);
                    pB2 = fmaf(hB[jj], wc.z, pB2);
                }
                #pragma unroll
                for (int off = 8; off > 0; off >>= 1) {
                    pA0 += __shfl_down(pA0, off, 16);
                    pA1 += __shfl_down(pA1, off, 16);
                    pA2 += __shfl_down(pA2, off, 16);
                    pB0 += __shfl_down(pB0, off, 16);
                    pB1 += __shfl_down(pB1, off, 16);
                    pB2 += __shfl_down(pB2, off, 16);
                }
                if (l == 0) {
                    Y[nodeA] = make_float4(pA0, pA1, pA2, 1.0f);
                    if (nodeB < nb1) Y[nodeB] = make_float4(pB0, pB1, pB2, 1.0f);
                }
            }
            __syncthreads();
        }
    }
    swbar(bar, NB);

    // ============ P2: per-bin counting sort -> ecsr + rowptr + Ys (196 blocks) =========
    if (bid < R) {
        if (tid < RNG) c[tid] = 0;
        if (tid < MAXB) sb[tid] = (tid < R) ? binCnt[tid] : 0;
        __syncthreads();
        int ecnt = sb[bid];
        int part = (tid < bid) ? sb[tid] : 0;        // prefix over bins < bid
        #pragma unroll
        for (int o = 32; o > 0; o >>= 1) part += __shfl_down(part, o, 64);
        if (lane == 0) swv[wid] = part;
        __syncthreads();
        if (tid == 0) {
            int s = 0;
            #pragma unroll
            for (int w = 0; w < 16; w++) s += swv[w];
            se0 = s;
        }
        __syncthreads();
        int eb0 = se0;
        size_t ebase = (size_t)bid * CAP;
        for (int e = tid; e < ecnt; e += NT) atomicAdd(&c[ebin[ebase + e] & (RNG - 1)], 1);
        __syncthreads();
        int v0 = (tid < RNG) ? c[tid] : 0;
        int sc = v0;                                 // wave-inclusive scan (waves 0-7)
        #pragma unroll
        for (int o = 1; o < 64; o <<= 1) {
            int t = __shfl_up(sc, o, 64);
            if (lane >= o) sc += t;
        }
        if (lane == 63 && wid < 8) swv[wid] = sc;
        __syncthreads();
        if (tid < 8) {                               // 8-wave exclusive offsets
            int v = swv[tid], s2 = v;
            #pragma unroll
            for (int o = 1; o < 8; o <<= 1) {
                int t = __shfl_up(s2, o, 8);
                if (tid >= o) s2 += t;
            }
            swv[tid] = s2 - v;
        }
        __syncthreads();
        if (tid < RNG) {
            int rp = eb0 + sc - v0 + swv[wid];       // CSR row start
            int n0 = bid * RNG + tid;
            if (n0 <= N) rowptr[n0] = rp;
            if (n0 < N) {
                float di = rsqrtf((float)v0 + 1.0f);
                float4 y = Y[n0];
                Ys[n0] = make_float4(di * y.x, di * y.y, di * y.z, di);  // y.w == 1
            }
            c[tid] = rp;                             // cursor
        }
        if (bid == R - 1 && tid == 0) rowptr[N] = E;
        if (bid == 0 && tid < 16) ecsr[E + tid] = 0; // slack for masked-12 gathers
        __syncthreads();
        for (int e = tid; e < ecnt; e += NT) {
            int ed = ebin[ebase + e];
            int pos = atomicAdd(&c[ed & (RNG - 1)], 1);    // LDS atomic
            ecsr[pos] = ed >> LB;
        }
    }
    swbar(bar, 2 * NB);

    // ============ P3: agg A — node-parallel over ALL 262k threads ============
    const int n = bid * NT + tid;
    int beg = 0, myDeg = 0;
    float myDi = 0.f;
    int si[12];
    if (n < N) {
        beg = rowptr[n];
        int end = rowptr[n + 1];
        myDeg = end - beg;
        myDi = rsqrtf((float)myDeg + 1.0f);
        float4 acc = Ys[n];
        int4 q0 = *(const int4*)(ecsr + beg);
        int4 q1 = *(const int4*)(ecsr + beg + 4);
        int4 q2 = *(const int4*)(ecsr + beg + 8);
        si[0] = q0.x; si[1] = q0.y; si[2]  = q0.z; si[3]  = q0.w;
        si[4] = q1.x; si[5] = q1.y; si[6]  = q1.z; si[7]  = q1.w;
        si[8] = q2.x; si[9] = q2.y; si[10] = q2.z; si[11] = q2.w;
        float4 g[12];
        #pragma unroll
        for (int k = 0; k < 12; k++) g[k] = Ys[si[k]];
        #pragma unroll
        for (int k = 0; k < 12; k++) if (k < myDeg) add4(acc, g[k]);
        for (int j = beg + 12; j < beg + myDeg; j++) add4(acc, Ys[ecsr[j]]);
        float d2 = myDi * myDi;
        Z1s[n] = make_float4(d2 * acc.x, d2 * acc.y, d2 * acc.z, d2 * acc.w);
    }
    swbar(bar, 3 * NB);

    // ============ P4: agg B + epilogue (si/beg/deg/di reused from registers) ==========
    if (n < N) {
        float4 acc = Z1s[n];
        float r = acc.w / myDi;                  // (Ahat*1)[n]
        float4 g[12];
        #pragma unroll
        for (int k = 0; k < 12; k++) g[k] = Z1s[si[k]];
        #pragma unroll
        for (int k = 0; k < 12; k++) if (k < myDeg) add4(acc, g[k]);
        for (int j = beg + 12; j < beg + myDeg; j++) add4(acc, Z1s[ecsr[j]]);
        float c0 = scb[0], c1 = scb[1], c2 = scb[2];
        float c3 = scb[3], c4 = scb[4], c5 = scb[5];
        out[(size_t)n * 3 + 0] = myDi * acc.x + r * c0 + c3;
        out[(size_t)n * 3 + 1] = myDi * acc.y + r * c1 + c4;
        out[(size_t)n * 3 + 2] = myDi * acc.z + r * c2 + c5;
    }
}

extern "C" void kernel_launch(void* const* d_in, const int* in_sizes, int n_in,
                              void* d_out, int out_size, void* d_ws, size_t ws_size,
                              hipStream_t stream) {
    const float* feat = (const float*)d_in[0];
    const int*   ei   = (const int*)d_in[1];
    // d_in[2] edge_type: unused (as in reference)
    const float* Win  = (const float*)d_in[3];
    const float* binp = (const float*)d_in[4];
    const float* W1   = (const float*)d_in[5];
    const float* b1   = (const float*)d_in[6];
    const float* W2   = (const float*)d_in[7];
    const float* b2   = (const float*)d_in[8];
    const float* Wout = (const float*)d_in[9];
    const float* bout = (const float*)d_in[10];
    float* out = (float*)d_out;

    int N = in_sizes[0] / DIN;
    int E = in_sizes[2];
    const int* src = ei;
    const int* dst = ei + E;

    int R = (N + RNG - 1) >> LB;            // 196 for N=100k
    int CHK = (E + NB - 1) / NB;            // edges per block in partition phase

    char* p = (char*)d_ws;
    auto alloc = [&](size_t bytes) -> char* {
        char* q = p;
        p += (bytes + 511) & ~(size_t)511;
        return q;
    };
    int*    binCnt = (int*)alloc((size_t)(MAXB + 128) * 4);   // binCnt + barrier
    int*    bar    = binCnt + MAXB;
    int*    ebin   = (int*)alloc((size_t)R * CAP * 4);        // 4.8 MB padded bins
    int*    ecsr   = (int*)alloc(((size_t)E + 16) * 4);
    int*    rowptr = (int*)alloc((size_t)(N + 1) * 4);
    float4* Y      = (float4*)alloc((size_t)N * 16);
    float4* Ys     = (float4*)alloc((size_t)N * 16);
    float4* Z1s    = (float4*)alloc((size_t)N * 16);

    hipMemsetAsync(binCnt, 0, (size_t)(MAXB + 128) * 4, stream);

    k_all<<<NB, NT, 0, stream>>>(feat, src, dst, Win, binp, W1, b1, W2, b2,
                                 Wout, bout, binCnt, bar, ebin, ecsr, rowptr,
                                 Y, Ys, Z1s, out, N, E, R, CHK);
}

// Round 8
// 192.532 us; speedup vs baseline: 3.3822x; 3.3822x over previous
//
#include <hip/hip_runtime.h>
#include <cstdint>

#define DIN 16
#define HD  128
#define NB  256     // grid = #CUs: all blocks co-resident (1024 thr = 16 waves <= 32/CU)
#define NT  1024
#define RNG 512     // nodes per bin
#define LB  9       // log2(RNG)
#define MAXB 256    // padded bin array
#define CAP 6144    // per-bin edge capacity (mean 4082, sigma ~64)

static __device__ __forceinline__ void fma4(float4& a, float s, const float4 v) {
    a.x = fmaf(s, v.x, a.x);
    a.y = fmaf(s, v.y, a.y);
    a.z = fmaf(s, v.z, a.z);
    a.w = fmaf(s, v.w, a.w);
}
static __device__ __forceinline__ void add4(float4& a, const float4 v) {
    a.x += v.x; a.y += v.y; a.z += v.z; a.w += v.w;
}
static __device__ __forceinline__ void lrelu4(float4& h) {
    h.x = h.x > 0.f ? h.x : 0.01f * h.x;
    h.y = h.y > 0.f ? h.y : 0.01f * h.y;
    h.z = h.z > 0.f ? h.z : 0.01f * h.z;
    h.w = h.w > 0.f ? h.w : 0.01f * h.w;
}

// Software grid barrier, leader-fence-only (ockl-style).
// R5/R6/R7 bug: per-thread __threadfence() = 16 waves x 256 blocks x 2 fences x
// 3 barriers = 24,576 wave-level buffer_wbl2+inv sequences serializing at the
// XCD L2s (~500 us, spin-mechanism independent). Fix: fences live ONLY on the
// block leader's atomics (256 per barrier):
//   - __syncthreads() drains vmcnt(0) -> block's writes ack'd at L2
//   - leader RELEASE fetch_add publishes the XCD L2 (wbl2)
//   - leader ACQUIRE load after spin emits buffer_inv: invalidates this CU's L1
//     (block is CU-resident -> covers all its waves) + stale XCD-L2 lines.
static __device__ __forceinline__ void swbar(int* bar, int target) {
    __syncthreads();                 // all block writes drained to L2 (vmcnt 0)
    if (threadIdx.x == 0) {
        __hip_atomic_fetch_add(bar, 1, __ATOMIC_RELEASE, __HIP_MEMORY_SCOPE_AGENT);
        int it = 0;
        while (__hip_atomic_load(bar, __ATOMIC_RELAXED,
                                 __HIP_MEMORY_SCOPE_AGENT) < target) {
            __builtin_amdgcn_s_sleep(8);         // ~0.2 us backoff
            if (++it > (1 << 20)) break;         // bounded: fail loudly, never hang
        }
        (void)__hip_atomic_load(bar, __ATOMIC_ACQUIRE,
                                __HIP_MEMORY_SCOPE_AGENT);   // one L1+L2 inv
    }
    __syncthreads();
}

__global__ __launch_bounds__(NT) void k_all(
    const float* __restrict__ F,
    const int* __restrict__ src, const int* __restrict__ dst,
    const float* __restrict__ Win, const float* __restrict__ binp,
    const float* __restrict__ W1, const float* __restrict__ b1,
    const float* __restrict__ W2, const float* __restrict__ b2,
    const float* __restrict__ Wout, const float* __restrict__ bout,
    int* __restrict__ binCnt, int* __restrict__ bar,
    int* __restrict__ ebin, int* __restrict__ ecsr, int* __restrict__ rowptr,
    float4* __restrict__ Y, float4* __restrict__ Ys, float4* __restrict__ Z1s,
    float* __restrict__ out, int N, int E, int R, int CHK)
{
    const int tid = threadIdx.x;
    const int bid = blockIdx.x;
    const int lane = tid & 63, wid = tid >> 6;

    __shared__ float  sT[HD * 3];           // W2@Wout (temp)
    __shared__ float4 sWinT[DIN * HD / 4];  // [k][c][l] : idx = k*32 + c*16 + l
    __shared__ float4 sWcT[HD];             // folded W1@W2@Wout, [jj][l]
    __shared__ float4 sBin[HD / 4];
    __shared__ float  sF[128 * DIN];
    __shared__ float  scb[8];               // c1[3], c2[3]
    __shared__ int    cnt[MAXB];
    __shared__ int    rsv[MAXB];
    __shared__ int    c[RNG];
    __shared__ int    sb[MAXB];
    __shared__ int    swv[16];
    __shared__ int    se0;

    // ============ P1a: partition — ALL blocks, CHK=E/256 edges each ============
    for (int i = tid; i < MAXB; i += NT) cnt[i] = 0;
    __syncthreads();
    int e0 = bid * CHK;
    int e1 = e0 + CHK; if (e1 > E) e1 = E;
    for (int e = e0 + tid; e < e1; e += NT) atomicAdd(&cnt[dst[e] >> LB], 1);
    __syncthreads();
    if (tid < MAXB) {
        int cc = cnt[tid];
        rsv[tid] = (tid < R && cc) ? atomicAdd(&binCnt[tid], cc) : 0;  // ~50k dev atomics
    }
    __syncthreads();
    for (int i = tid; i < MAXB; i += NT) cnt[i] = 0;   // reuse as local cursor
    __syncthreads();
    for (int e = e0 + tid; e < e1; e += NT) {
        int s = src[e], d = dst[e];
        int bb = d >> LB;
        int lp = atomicAdd(&cnt[bb], 1);               // LDS atomic
        ebin[(size_t)bb * CAP + rsv[bb] + lp] = (s << LB) | (d & (RNG - 1));
    }

    // ============ P1b: weight fold (redundant per block, all in LDS) ============
    if (tid < DIN * HD / 4) {               // stage Win (512 float4)
        int k = tid >> 5, rem = tid & 31, l = rem >> 1, cc = rem & 1;
        sWinT[k * 32 + cc * 16 + l] = ((const float4*)Win)[tid];
    } else if (tid < DIN * HD / 4 + HD / 4) {
        int i = tid - DIN * HD / 4;
        sBin[i] = ((const float4*)binp)[i];
    }
    for (int idx = tid; idx < HD * 3; idx += NT) {     // sT = W2 @ Wout
        int k = idx / 3, o = idx - 3 * k;
        float s = 0.f;
        for (int j = 0; j < HD; j++) s = fmaf(W2[k * HD + j], Wout[j * 3 + o], s);
        sT[idx] = s;
    }
    __syncthreads();
    for (int idx = tid; idx < HD * 3; idx += NT) {     // Wc = W1 @ sT
        int k = idx / 3, o = idx - 3 * k;
        float s = 0.f;
        for (int j = 0; j < HD; j++) s = fmaf(W1[k * HD + j], sT[j * 3 + o], s);
        ((float*)&sWcT[(k & 7) * 16 + (k >> 3)])[o] = s;
    }
    if (tid < HD) ((float*)&sWcT[(tid & 7) * 16 + (tid >> 3)])[3] = 0.f;
    if (tid < 3) {                          // c2 = Wout^T b2 + bout ; c1 = sT^T b1
        float s2v = bout[tid];
        for (int j = 0; j < HD; j++) s2v = fmaf(b2[j], Wout[j * 3 + tid], s2v);
        scb[3 + tid] = s2v;
        float s1 = 0.f;
        for (int j = 0; j < HD; j++) s1 = fmaf(b1[j], sT[j * 3 + tid], s1);
        scb[tid] = s1;
    }
    __syncthreads();

    // ============ P1c: input MLP — ALL blocks, 391 nodes each ============
    {
        int nper = (N + NB - 1) / NB;
        int nb0 = bid * nper;
        int nb1 = nb0 + nper; if (nb1 > N) nb1 = N;
        for (int cb = nb0; cb < nb1; cb += 128) {
            {
                int n0 = cb + (tid >> 4);
                sF[tid] = (n0 < N) ? F[(size_t)cb * DIN + tid] : 0.f;
                int n1 = cb + ((tid + 1024) >> 4);
                sF[tid + 1024] = (n1 < N) ? F[(size_t)cb * DIN + tid + 1024] : 0.f;
            }
            __syncthreads();
            int l = tid & 15;
            int g = tid >> 4;
            int nodeA = cb + 2 * g;
            int nodeB = nodeA + 1;
            if (nodeA < nb1) {
                float4 a0 = sBin[l * 2 + 0], a1 = sBin[l * 2 + 1];
                float4 b0 = a0, b1v = a1;
                #pragma unroll
                for (int k = 0; k < DIN; k++) {
                    float4 w0 = sWinT[k * 32 + l];
                    float4 w1 = sWinT[k * 32 + 16 + l];
                    float fA = sF[(2 * g) * DIN + k];
                    float fB = sF[(2 * g + 1) * DIN + k];
                    fma4(a0, fA, w0); fma4(a1, fA, w1);
                    fma4(b0, fB, w0); fma4(b1v, fB, w1);
                }
                lrelu4(a0); lrelu4(a1); lrelu4(b0); lrelu4(b1v);
                float hA[8] = {a0.x, a0.y, a0.z, a0.w, a1.x, a1.y, a1.z, a1.w};
                float hB[8] = {b0.x, b0.y, b0.z, b0.w, b1v.x, b1v.y, b1v.z, b1v.w};
                float pA0 = 0.f, pA1 = 0.f, pA2 = 0.f, pB0 = 0.f, pB1 = 0.f, pB2 = 0.f;
                #pragma unroll
                for (int jj = 0; jj < 8; jj++) {
                    float4 wc = sWcT[jj * 16 + l];
                    pA0 = fmaf(hA[jj], wc.x, pA0);
                    pA1 = fmaf(hA[jj], wc.y, pA1);
                    pA2 = fmaf(hA[jj], wc.z, pA2);
                    pB0 = fmaf(hB[jj], wc.x, pB0);
                    pB1 = fmaf(hB[jj], wc.y, pB1);
                    pB2 = fmaf(hB[jj], wc.z, pB2);
                }
                #pragma unroll
                for (int off = 8; off > 0; off >>= 1) {
                    pA0 += __shfl_down(pA0, off, 16);
                    pA1 += __shfl_down(pA1, off, 16);
                    pA2 += __shfl_down(pA2, off, 16);
                    pB0 += __shfl_down(pB0, off, 16);
                    pB1 += __shfl_down(pB1, off, 16);
                    pB2 += __shfl_down(pB2, off, 16);
                }
                if (l == 0) {
                    Y[nodeA] = make_float4(pA0, pA1, pA2, 1.0f);
                    if (nodeB < nb1) Y[nodeB] = make_float4(pB0, pB1, pB2, 1.0f);
                }
            }
            __syncthreads();
        }
    }
    swbar(bar, NB);

    // ============ P2: per-bin counting sort -> ecsr + rowptr + Ys (196 blocks) =========
    if (bid < R) {
        if (tid < RNG) c[tid] = 0;
        if (tid < MAXB) sb[tid] = (tid < R) ? binCnt[tid] : 0;
        __syncthreads();
        int ecnt = sb[bid];
        int part = (tid < bid) ? sb[tid] : 0;        // prefix over bins < bid
        #pragma unroll
        for (int o = 32; o > 0; o >>= 1) part += __shfl_down(part, o, 64);
        if (lane == 0) swv[wid] = part;
        __syncthreads();
        if (tid == 0) {
            int s = 0;
            #pragma unroll
            for (int w = 0; w < 16; w++) s += swv[w];
            se0 = s;
        }
        __syncthreads();
        int eb0 = se0;
        size_t ebase = (size_t)bid * CAP;
        for (int e = tid; e < ecnt; e += NT) atomicAdd(&c[ebin[ebase + e] & (RNG - 1)], 1);
        __syncthreads();
        int v0 = (tid < RNG) ? c[tid] : 0;
        int sc = v0;                                 // wave-inclusive scan (waves 0-7)
        #pragma unroll
        for (int o = 1; o < 64; o <<= 1) {
            int t = __shfl_up(sc, o, 64);
            if (lane >= o) sc += t;
        }
        if (lane == 63 && wid < 8) swv[wid] = sc;
        __syncthreads();
        if (tid < 8) {                               // 8-wave exclusive offsets
            int v = swv[tid], s2 = v;
            #pragma unroll
            for (int o = 1; o < 8; o <<= 1) {
                int t = __shfl_up(s2, o, 8);
                if (tid >= o) s2 += t;
            }
            swv[tid] = s2 - v;
        }
        __syncthreads();
        if (tid < RNG) {
            int rp = eb0 + sc - v0 + swv[wid];       // CSR row start
            int n0 = bid * RNG + tid;
            if (n0 <= N) rowptr[n0] = rp;
            if (n0 < N) {
                float di = rsqrtf((float)v0 + 1.0f);
                float4 y = Y[n0];
                Ys[n0] = make_float4(di * y.x, di * y.y, di * y.z, di);  // y.w == 1
            }
            c[tid] = rp;                             // cursor
        }
        if (bid == R - 1 && tid == 0) rowptr[N] = E;
        if (bid == 0 && tid < 16) ecsr[E + tid] = 0; // slack for masked-12 gathers
        __syncthreads();
        for (int e = tid; e < ecnt; e += NT) {
            int ed = ebin[ebase + e];
            int pos = atomicAdd(&c[ed & (RNG - 1)], 1);    // LDS atomic
            ecsr[pos] = ed >> LB;
        }
    }
    swbar(bar, 2 * NB);

    // ============ P3: agg A — node-parallel over ALL 262k threads ============
    const int n = bid * NT + tid;
    int beg = 0, myDeg = 0;
    float myDi = 0.f;
    int si[12];
    if (n < N) {
        beg = rowptr[n];
        int end = rowptr[n + 1];
        myDeg = end - beg;
        myDi = rsqrtf((float)myDeg + 1.0f);
        float4 acc = Ys[n];
        int4 q0 = *(const int4*)(ecsr + beg);
        int4 q1 = *(const int4*)(ecsr + beg + 4);
        int4 q2 = *(const int4*)(ecsr + beg + 8);
        si[0] = q0.x; si[1] = q0.y; si[2]  = q0.z; si[3]  = q0.w;
        si[4] = q1.x; si[5] = q1.y; si[6]  = q1.z; si[7]  = q1.w;
        si[8] = q2.x; si[9] = q2.y; si[10] = q2.z; si[11] = q2.w;
        float4 g[12];
        #pragma unroll
        for (int k = 0; k < 12; k++) g[k] = Ys[si[k]];
        #pragma unroll
        for (int k = 0; k < 12; k++) if (k < myDeg) add4(acc, g[k]);
        for (int j = beg + 12; j < beg + myDeg; j++) add4(acc, Ys[ecsr[j]]);
        float d2 = myDi * myDi;
        Z1s[n] = make_float4(d2 * acc.x, d2 * acc.y, d2 * acc.z, d2 * acc.w);
    }
    swbar(bar, 3 * NB);

    // ============ P4: agg B + epilogue (si/beg/deg/di reused from registers) ==========
    if (n < N) {
        float4 acc = Z1s[n];
        float r = acc.w / myDi;                  // (Ahat*1)[n]
        float4 g[12];
        #pragma unroll
        for (int k = 0; k < 12; k++) g[k] = Z1s[si[k]];
        #pragma unroll
        for (int k = 0; k < 12; k++) if (k < myDeg) add4(acc, g[k]);
        for (int j = beg + 12; j < beg + myDeg; j++) add4(acc, Z1s[ecsr[j]]);
        float c0 = scb[0], c1 = scb[1], c2 = scb[2];
        float c3 = scb[3], c4 = scb[4], c5 = scb[5];
        out[(size_t)n * 3 + 0] = myDi * acc.x + r * c0 + c3;
        out[(size_t)n * 3 + 1] = myDi * acc.y + r * c1 + c4;
        out[(size_t)n * 3 + 2] = myDi * acc.z + r * c2 + c5;
    }
}

extern "C" void kernel_launch(void* const* d_in, const int* in_sizes, int n_in,
                              void* d_out, int out_size, void* d_ws, size_t ws_size,
                              hipStream_t stream) {
    const float* feat = (const float*)d_in[0];
    const int*   ei   = (const int*)d_in[1];
    // d_in[2] edge_type: unused (as in reference)
    const float* Win  = (const float*)d_in[3];
    const float* binp = (const float*)d_in[4];
    const float* W1   = (const float*)d_in[5];
    const float* b1   = (const float*)d_in[6];
    const float* W2   = (const float*)d_in[7];
    const float* b2   = (const float*)d_in[8];
    const float* Wout = (const float*)d_in[9];
    const float* bout = (const float*)d_in[10];
    float* out = (float*)d_out;

    int N = in_sizes[0] / DIN;
    int E = in_sizes[2];
    const int* src = ei;
    const int* dst = ei + E;

    int R = (N + RNG - 1) >> LB;            // 196 for N=100k
    int CHK = (E + NB - 1) / NB;            // edges per block in partition phase

    char* p = (char*)d_ws;
    auto alloc = [&](size_t bytes) -> char* {
        char* q = p;
        p += (bytes + 511) & ~(size_t)511;
        return q;
    };
    int*    binCnt = (int*)alloc((size_t)(MAXB + 128) * 4);   // binCnt + barrier
    int*    bar    = binCnt + MAXB;
    int*    ebin   = (int*)alloc((size_t)R * CAP * 4);        // 4.8 MB padded bins
    int*    ecsr   = (int*)alloc(((size_t)E + 16) * 4);
    int*    rowptr = (int*)alloc((size_t)(N + 1) * 4);
    float4* Y      = (float4*)alloc((size_t)N * 16);
    float4* Ys     = (float4*)alloc((size_t)N * 16);
    float4* Z1s    = (float4*)alloc((size_t)N * 16);

    hipMemsetAsync(binCnt, 0, (size_t)(MAXB + 128) * 4, stream);

    k_all<<<NB, NT, 0, stream>>>(feat, src, dst, Win, binp, W1, b1, W2, b2,
                                 Wout, bout, binCnt, bar, ebin, ecsr, rowptr,
                                 Y, Ys, Z1s, out, N, E, R, CHK);
}

// Round 9
// 188.481 us; speedup vs baseline: 3.4549x; 1.0215x over previous
//
#include <hip/hip_runtime.h>
#include <cstdint>

#define DIN  16
#define HD   128
#define NB   256    // grid = #CUs: all blocks co-resident (16 waves <= 32/CU)
#define NT   1024
#define NBIN 256    // bins == blocks: every block owns exactly one bin
#define CAP  4096   // per-bin edge capacity (mean ~3125, sigma ~56)
#define WMAX 512    // max nodes per bin (K >= 256 since N <= 131072)

static __device__ __forceinline__ void fma4(float4& a, float s, const float4 v) {
    a.x = fmaf(s, v.x, a.x);
    a.y = fmaf(s, v.y, a.y);
    a.z = fmaf(s, v.z, a.z);
    a.w = fmaf(s, v.w, a.w);
}
static __device__ __forceinline__ void lrelu4(float4& h) {
    h.x = h.x > 0.f ? h.x : 0.01f * h.x;
    h.y = h.y > 0.f ? h.y : 0.01f * h.y;
    h.z = h.z > 0.f ? h.z : 0.01f * h.z;
    h.w = h.w > 0.f ? h.w : 0.01f * h.w;
}

// Leader-fence-only grid barrier — exact R8 version (proven: ~us-scale, correct).
static __device__ __forceinline__ void swbar(int* bar, int target) {
    __syncthreads();                 // all block writes drained to L2 (vmcnt 0)
    if (threadIdx.x == 0) {
        __hip_atomic_fetch_add(bar, 1, __ATOMIC_RELEASE, __HIP_MEMORY_SCOPE_AGENT);
        int it = 0;
        while (__hip_atomic_load(bar, __ATOMIC_RELAXED,
                                 __HIP_MEMORY_SCOPE_AGENT) < target) {
            __builtin_amdgcn_s_sleep(8);
            if (++it > (1 << 20)) break;         // bounded: fail loudly, never hang
        }
        (void)__hip_atomic_load(bar, __ATOMIC_ACQUIRE,
                                __HIP_MEMORY_SCOPE_AGENT);   // one L1+L2 inv
    }
    __syncthreads();
}

// Phases: P1 partition+fold+MLP | B deg+Ys | C aggA (LDS acc) | D aggB + epilogue.
// Assumes E <= NB*CAP edges total per bin window and uniform-ish dst (CAP margin 17 sigma).
__global__ __launch_bounds__(NT) void k_all(
    const float* __restrict__ F,
    const int* __restrict__ src, const int* __restrict__ dst,
    const float* __restrict__ Win, const float* __restrict__ binp,
    const float* __restrict__ W1, const float* __restrict__ b1,
    const float* __restrict__ W2, const float* __restrict__ b2,
    const float* __restrict__ Wout, const float* __restrict__ bout,
    int* __restrict__ binCnt, int* __restrict__ bar, int* __restrict__ ebin,
    float4* __restrict__ Ys, float4* __restrict__ Z1s,
    float* __restrict__ out, int N, int E, int K, int CHK)
{
    const int tid = threadIdx.x;
    const int bid = blockIdx.x;

    __shared__ float  sT[HD * 3];           // W2@Wout (temp)
    __shared__ float4 sWinT[DIN * HD / 4];  // [k][c][l] : idx = k*32 + c*16 + l
    __shared__ float4 sWcT[HD];             // folded W1@W2@Wout, [jj][l]
    __shared__ float4 sBin[HD / 4];
    __shared__ float  sF[128 * DIN];
    __shared__ float  scb[8];               // c1[3], c2[3]
    __shared__ float4 sY[WMAX];             // MLP output for this bin (never global)
    __shared__ int    sbase[NBIN + 1];      // bin -> first node
    __shared__ int    cnt[NBIN];
    __shared__ int    rsv[NBIN];
    __shared__ int    ideg[WMAX];
    __shared__ float  sdi[WMAX];
    __shared__ float  srw[WMAX];            // r = Z1s_self.w / di (pre-accumulation!)
    __shared__ float  accf[WMAX * 5];       // stride-5: bank-conflict-free atomics

    // ---- bin base table: base(b) = ceil(b<<17 / K), clamped to N ----
    for (int i = tid; i <= NBIN; i += NT) {
        long long t = ((long long)i << 17) + (K - 1);
        int b = (int)(t / K);
        sbase[i] = b > N ? N : b;
    }
    if (tid < NBIN) cnt[tid] = 0;
    __syncthreads();

    // ============ P1a: partition — count / reserve / place ============
    const int e0 = bid * CHK;
    const int e1 = min(e0 + CHK, E);
    #pragma unroll
    for (int t = 0; t < 4; t++) {
        int e = e0 + tid + t * NT;
        if (e < e1) atomicAdd(&cnt[((unsigned)dst[e] * (unsigned)K) >> 17], 1);
    }
    __syncthreads();
    if (tid < NBIN) {
        int cc = cnt[tid];
        rsv[tid] = cc ? atomicAdd(&binCnt[tid], cc) : 0;   // ~sparse dev atomics
    }
    __syncthreads();
    if (tid < NBIN) cnt[tid] = 0;                          // reuse as cursor
    __syncthreads();
    #pragma unroll
    for (int t = 0; t < 4; t++) {
        int e = e0 + tid + t * NT;
        if (e < e1) {
            int s = src[e], d = dst[e];
            int bb = ((unsigned)d * (unsigned)K) >> 17;
            int lp = atomicAdd(&cnt[bb], 1);               // LDS atomic
            ebin[bb * CAP + rsv[bb] + lp] = (s << 9) | (d - sbase[bb]);
        }
    }

    // ============ P1b: weight fold (redundant per block, all in LDS) ============
    if (tid < DIN * HD / 4) {               // stage Win (512 float4)
        int k = tid >> 5, rem = tid & 31, l = rem >> 1, cc = rem & 1;
        sWinT[k * 32 + cc * 16 + l] = ((const float4*)Win)[tid];
    } else if (tid < DIN * HD / 4 + HD / 4) {
        int i = tid - DIN * HD / 4;
        sBin[i] = ((const float4*)binp)[i];
    }
    for (int idx = tid; idx < HD * 3; idx += NT) {     // sT = W2 @ Wout
        int k = idx / 3, o = idx - 3 * k;
        float s = 0.f;
        for (int j = 0; j < HD; j++) s = fmaf(W2[k * HD + j], Wout[j * 3 + o], s);
        sT[idx] = s;
    }
    __syncthreads();
    for (int idx = tid; idx < HD * 3; idx += NT) {     // Wc = W1 @ sT
        int k = idx / 3, o = idx - 3 * k;
        float s = 0.f;
        for (int j = 0; j < HD; j++) s = fmaf(W1[k * HD + j], sT[j * 3 + o], s);
        ((float*)&sWcT[(k & 7) * 16 + (k >> 3)])[o] = s;
    }
    if (tid < HD) ((float*)&sWcT[(tid & 7) * 16 + (tid >> 3)])[3] = 0.f;
    if (tid < 3) {                          // c2 = Wout^T b2 + bout ; c1 = sT^T b1
        float s2v = bout[tid];
        for (int j = 0; j < HD; j++) s2v = fmaf(b2[j], Wout[j * 3 + tid], s2v);
        scb[3 + tid] = s2v;
        float s1 = 0.f;
        for (int j = 0; j < HD; j++) s1 = fmaf(b1[j], sT[j * 3 + tid], s1);
        scb[tid] = s1;
    }
    __syncthreads();

    // ============ P1c: input MLP over this block's bin -> sY (LDS only) ============
    const int base = sbase[bid];
    const int W = sbase[bid + 1] - base;                   // 0..512
    for (int cb = base; cb < base + W; cb += 128) {
        {
            int n0 = cb + (tid >> 4);
            sF[tid] = (n0 < N) ? F[(size_t)cb * DIN + tid] : 0.f;
            int n1 = cb + ((tid + 1024) >> 4);
            sF[tid + 1024] = (n1 < N) ? F[(size_t)cb * DIN + tid + 1024] : 0.f;
        }
        __syncthreads();
        int l = tid & 15;
        int g = tid >> 4;
        int nodeA = cb + 2 * g;
        int nodeB = nodeA + 1;
        if (nodeA < base + W) {
            float4 a0 = sBin[l * 2 + 0], a1 = sBin[l * 2 + 1];
            float4 b0 = a0, b1v = a1;
            #pragma unroll
            for (int k = 0; k < DIN; k++) {
                float4 w0 = sWinT[k * 32 + l];
                float4 w1 = sWinT[k * 32 + 16 + l];
                float fA = sF[(2 * g) * DIN + k];
                float fB = sF[(2 * g + 1) * DIN + k];
                fma4(a0, fA, w0); fma4(a1, fA, w1);
                fma4(b0, fB, w0); fma4(b1v, fB, w1);
            }
            lrelu4(a0); lrelu4(a1); lrelu4(b0); lrelu4(b1v);
            float hA[8] = {a0.x, a0.y, a0.z, a0.w, a1.x, a1.y, a1.z, a1.w};
            float hB[8] = {b0.x, b0.y, b0.z, b0.w, b1v.x, b1v.y, b1v.z, b1v.w};
            float pA0 = 0.f, pA1 = 0.f, pA2 = 0.f, pB0 = 0.f, pB1 = 0.f, pB2 = 0.f;
            #pragma unroll
            for (int jj = 0; jj < 8; jj++) {
                float4 wc = sWcT[jj * 16 + l];
                pA0 = fmaf(hA[jj], wc.x, pA0);
                pA1 = fmaf(hA[jj], wc.y, pA1);
                pA2 = fmaf(hA[jj], wc.z, pA2);
                pB0 = fmaf(hB[jj], wc.x, pB0);
                pB1 = fmaf(hB[jj], wc.y, pB1);
                pB2 = fmaf(hB[jj], wc.z, pB2);
            }
            #pragma unroll
            for (int off = 8; off > 0; off >>= 1) {
                pA0 += __shfl_down(pA0, off, 16);
                pA1 += __shfl_down(pA1, off, 16);
                pA2 += __shfl_down(pA2, off, 16);
                pB0 += __shfl_down(pB0, off, 16);
                pB1 += __shfl_down(pB1, off, 16);
                pB2 += __shfl_down(pB2, off, 16);
            }
            if (l == 0) {
                sY[nodeA - base] = make_float4(pA0, pA1, pA2, 1.0f);
                if (nodeB < base + W) sY[nodeB - base] = make_float4(pB0, pB1, pB2, 1.0f);
            }
        }
        __syncthreads();
    }
    swbar(bar, NB);

    // ============ B: per-node degree from own bin -> di, Ys, acc init ============
    const int ecnt = binCnt[bid];           // <= CAP
    const int eb = bid * CAP;
    for (int i = tid; i < WMAX; i += NT) ideg[i] = 0;
    __syncthreads();
    int pk[4];                              // bin edge stream, kept in regs for B/C/D
    #pragma unroll
    for (int t = 0; t < 4; t++) pk[t] = ebin[eb + tid + t * NT];   // always in-bounds
    #pragma unroll
    for (int t = 0; t < 4; t++)
        if (tid + t * NT < ecnt) atomicAdd(&ideg[pk[t] & 511], 1);
    __syncthreads();
    for (int i = tid; i < W; i += NT) {
        float di = rsqrtf((float)ideg[i] + 1.0f);
        float4 y = sY[i];
        Ys[base + i] = make_float4(di * y.x, di * y.y, di * y.z, di);
        sdi[i] = di;
        accf[i * 5 + 0] = di * y.x;
        accf[i * 5 + 1] = di * y.y;
        accf[i * 5 + 2] = di * y.z;
        accf[i * 5 + 3] = di;
    }
    swbar(bar, 2 * NB);

    // ============ C: agg A — gather Ys[src], LDS-atomic accumulate ============
    {
        float4 g[4];
        #pragma unroll
        for (int t = 0; t < 4; t++)
            if (tid + t * NT < ecnt) g[t] = Ys[pk[t] >> 9];
        #pragma unroll
        for (int t = 0; t < 4; t++)
            if (tid + t * NT < ecnt) {
                int a5 = (pk[t] & 511) * 5;
                atomicAdd(&accf[a5 + 0], g[t].x);
                atomicAdd(&accf[a5 + 1], g[t].y);
                atomicAdd(&accf[a5 + 2], g[t].z);
                atomicAdd(&accf[a5 + 3], g[t].w);
            }
    }
    __syncthreads();
    for (int i = tid; i < W; i += NT) {
        float di = sdi[i], d2 = di * di;
        float zx = d2 * accf[i * 5 + 0];
        float zy = d2 * accf[i * 5 + 1];
        float zz = d2 * accf[i * 5 + 2];
        float zw = d2 * accf[i * 5 + 3];
        Z1s[base + i] = make_float4(zx, zy, zz, zw);
        srw[i] = zw / di;                   // r = self Z1s.w / di, BEFORE D's adds
        accf[i * 5 + 0] = zx;
        accf[i * 5 + 1] = zy;
        accf[i * 5 + 2] = zz;               // .w not needed in D
    }
    swbar(bar, 3 * NB);

    // ============ D: agg B — gather Z1s[src], accumulate, epilogue ============
    {
        float4 g[4];
        #pragma unroll
        for (int t = 0; t < 4; t++)
            if (tid + t * NT < ecnt) g[t] = Z1s[pk[t] >> 9];
        #pragma unroll
        for (int t = 0; t < 4; t++)
            if (tid + t * NT < ecnt) {
                int a5 = (pk[t] & 511) * 5;
                atomicAdd(&accf[a5 + 0], g[t].x);
                atomicAdd(&accf[a5 + 1], g[t].y);
                atomicAdd(&accf[a5 + 2], g[t].z);
            }
    }
    __syncthreads();
    for (int i = tid; i < W; i += NT) {
        float di = sdi[i];
        float r  = srw[i];
        int n = base + i;
        out[(size_t)n * 3 + 0] = di * accf[i * 5 + 0] + r * scb[0] + scb[3];
        out[(size_t)n * 3 + 1] = di * accf[i * 5 + 1] + r * scb[1] + scb[4];
        out[(size_t)n * 3 + 2] = di * accf[i * 5 + 2] + r * scb[2] + scb[5];
    }
}

extern "C" void kernel_launch(void* const* d_in, const int* in_sizes, int n_in,
                              void* d_out, int out_size, void* d_ws, size_t ws_size,
                              hipStream_t stream) {
    const float* feat = (const float*)d_in[0];
    const int*   ei   = (const int*)d_in[1];
    // d_in[2] edge_type: unused (as in reference)
    const float* Win  = (const float*)d_in[3];
    const float* binp = (const float*)d_in[4];
    const float* W1   = (const float*)d_in[5];
    const float* b1   = (const float*)d_in[6];
    const float* W2   = (const float*)d_in[7];
    const float* b2   = (const float*)d_in[8];
    const float* Wout = (const float*)d_in[9];
    const float* bout = (const float*)d_in[10];
    float* out = (float*)d_out;

    int N = in_sizes[0] / DIN;
    int E = in_sizes[2];
    const int* src = ei;
    const int* dst = ei + E;

    // bin(d) = (d*K)>>17 -> 256 balanced bins, width <= 512 for N <= 131072
    int K = (int)(((long long)NBIN << 17) / N);    // 335 for N=100k
    int CHK = (E + NB - 1) / NB;                   // 3125 edges per partition block

    char* p = (char*)d_ws;
    auto alloc = [&](size_t bytes) -> char* {
        char* q = p;
        p += (bytes + 511) & ~(size_t)511;
        return q;
    };
    int*    binCnt = (int*)alloc((size_t)(NBIN + 128) * 4);   // binCnt + barrier
    int*    bar    = binCnt + NBIN;
    int*    ebin   = (int*)alloc((size_t)NBIN * CAP * 4);     // 4 MB padded bins
    float4* Ysb    = (float4*)alloc((size_t)N * 16);
    float4* Z1s    = (float4*)alloc((size_t)N * 16);

    hipMemsetAsync(binCnt, 0, (size_t)(NBIN + 128) * 4, stream);

    k_all<<<NB, NT, 0, stream>>>(feat, src, dst, Win, binp, W1, b1, W2, b2,
                                 Wout, bout, binCnt, bar, ebin,
                                 Ysb, Z1s, out, N, E, K, CHK);
}